// Round 2
// baseline (47616.071 us; speedup 1.0000x reference)
//
#include <hip/hip_runtime.h>
#include <cstddef>

#define T_LEN 131072
#define NPF 8   // prefetch distance (steps) for gate pre-activations

typedef float float2_t __attribute__((ext_vector_type(2)));
typedef float float4_t __attribute__((ext_vector_type(4)));

__device__ __forceinline__ float fast_sigmoid(float x) {
  // 1/(1+exp(-x)); exp via v_exp_f32, rcp via v_rcp_f32 (~1 ulp each)
  float e = __builtin_amdgcn_exp2f(x * -1.44269504088896340736f);
  return __builtin_amdgcn_rcpf(1.0f + e);
}

__device__ __forceinline__ float fast_tanh(float x) {
  // tanh(x) = 1 - 2/(1+exp(2x)); saturates correctly at +/-inf
  float e = __builtin_amdgcn_exp2f(x * 2.88539008177792681472f);
  return 1.0f - 2.0f * __builtin_amdgcn_rcpf(1.0f + e);
}

// ---------------------------------------------------------------------------
// Kernel A (parallel over T): hs_in = relu(x@W1+b1); gates[t] = hs_in @ {Wir,Wiz,Win} + b
// gates layout: [T][3][64] fp32
// ---------------------------------------------------------------------------
__global__ __launch_bounds__(256) void prep_kernel(
    const float* __restrict__ obs, const float* __restrict__ W1,
    const float* __restrict__ b1,
    const float* __restrict__ Wir, const float* __restrict__ bir,
    const float* __restrict__ Wiz, const float* __restrict__ biz,
    const float* __restrict__ Win, const float* __restrict__ bin,
    float* __restrict__ gates)
{
  __shared__ float sW1[36 * 64];
  __shared__ float sWg[3 * 4096];
  __shared__ float sb1[64];
  __shared__ float sbg[3 * 64];
  for (int i = threadIdx.x; i < 36 * 64; i += 256) sW1[i] = W1[i];
  for (int i = threadIdx.x; i < 4096; i += 256) {
    sWg[i] = Wir[i];
    sWg[4096 + i] = Wiz[i];
    sWg[8192 + i] = Win[i];
  }
  if (threadIdx.x < 64) {
    sb1[threadIdx.x] = b1[threadIdx.x];
    sbg[threadIdx.x] = bir[threadIdx.x];
    sbg[64 + threadIdx.x] = biz[threadIdx.x];
    sbg[128 + threadIdx.x] = bin[threadIdx.x];
  }
  __syncthreads();

  const int t = blockIdx.x * 256 + threadIdx.x;   // T divisible by 256

  float4_t x4[9];
  {
    const float4_t* op = (const float4_t*)(obs + (size_t)t * 36);
#pragma unroll
    for (int c = 0; c < 9; c++) x4[c] = op[c];
  }
  float4_t hacc[16];
  {
    const float4_t* bv = (const float4_t*)sb1;
#pragma unroll
    for (int k = 0; k < 16; k++) hacc[k] = bv[k];
  }
#pragma unroll
  for (int c = 0; c < 9; c++) {
#pragma unroll
    for (int q = 0; q < 4; q++) {
      const float xv = x4[c][q];
      const float4_t* wrow = (const float4_t*)(sW1 + (c * 4 + q) * 64);
#pragma unroll
      for (int k = 0; k < 16; k++) hacc[k] += xv * wrow[k];
    }
  }
#pragma unroll
  for (int k = 0; k < 16; k++) {
    hacc[k].x = fmaxf(hacc[k].x, 0.0f);
    hacc[k].y = fmaxf(hacc[k].y, 0.0f);
    hacc[k].z = fmaxf(hacc[k].z, 0.0f);
    hacc[k].w = fmaxf(hacc[k].w, 0.0f);
  }

  float* gout = gates + (size_t)t * 192;
  for (int g = 0; g < 3; g++) {   // rolled: caps register pressure
    const float* wg = sWg + g * 4096;
    float4_t acc[16];
    {
      const float4_t* bv = (const float4_t*)(sbg + g * 64);
#pragma unroll
      for (int k = 0; k < 16; k++) acc[k] = bv[k];
    }
#pragma unroll
    for (int ii = 0; ii < 16; ii++) {
      const float4_t hv4 = hacc[ii];
#pragma unroll
      for (int q = 0; q < 4; q++) {
        const float hv = hv4[q];
        const float4_t* wrow = (const float4_t*)(wg + (ii * 4 + q) * 64);
#pragma unroll
        for (int k = 0; k < 16; k++) acc[k] += hv * wrow[k];
      }
    }
    float4_t* outp = (float4_t*)(gout + g * 64);
#pragma unroll
    for (int k = 0; k < 16; k++) outp[k] = acc[k];
  }
}

// ---------------------------------------------------------------------------
// Kernel B (sequential): single wave, lane j owns hidden unit j.
// FP32 THROUGHOUT — fp16 weights drift ~0.7 absmax over 131k steps (R1 fail).
// Weight columns in registers as float2 pairs; matvec via v_pk_fma_f32
// (__builtin_elementwise_fma on float2). h broadcast through a 256B LDS
// buffer (uniform-address ds_read_b128 = free broadcast).
// ---------------------------------------------------------------------------
__global__ __launch_bounds__(64, 1) void scan_kernel(
    const float* __restrict__ gates,
    const float* __restrict__ Whr, const float* __restrict__ Whz,
    const float* __restrict__ Whn, const float* __restrict__ bhn,
    float* __restrict__ hs)
{
  __shared__ float sW[3 * 4096];
  __shared__ __align__(16) float hbuf[64];
  const int j = threadIdx.x;

  // stage weights coalesced, then pull column j into float2 register pairs
  for (int i = j; i < 4096; i += 64) {
    sW[i] = Whr[i];
    sW[4096 + i] = Whz[i];
    sW[8192 + i] = Whn[i];
  }
  __syncthreads();

  float2_t wr[32], wz[32], wn[32];
#pragma unroll
  for (int k = 0; k < 32; k++) {
    wr[k] = float2_t{sW[(2 * k) * 64 + j],        sW[(2 * k + 1) * 64 + j]};
    wz[k] = float2_t{sW[4096 + (2 * k) * 64 + j], sW[4096 + (2 * k + 1) * 64 + j]};
    wn[k] = float2_t{sW[8192 + (2 * k) * 64 + j], sW[8192 + (2 * k + 1) * 64 + j]};
  }
  const float bh = bhn[j];

  float h = 0.0f;
  hbuf[j] = 0.0f;
  __syncthreads();

  // software-pipelined gate loads, distance NPF steps
  float pr[NPF], pz[NPF], pn[NPF];
  {
    const float* g0 = gates + j;
#pragma unroll
    for (int d = 0; d < NPF; d++) {
      pr[d] = g0[(size_t)d * 192];
      pz[d] = g0[(size_t)d * 192 + 64];
      pn[d] = g0[(size_t)d * 192 + 128];
    }
  }
  const float* gpf = gates + j + (size_t)NPF * 192;  // runs NPF*768B past end: lands in hs region (values discarded, safe)
  float* hp = hs + j;

  for (int tb = 0; tb < T_LEN / NPF; tb++) {
#pragma unroll
    for (int d = 0; d < NPF; d++) {
      const float xr = pr[d], xz = pz[d], xn = pn[d];
      pr[d] = gpf[0];
      pz[d] = gpf[64];
      pn[d] = gpf[128];
      gpf += 192;

      float2_t ar0 = {0.f, 0.f}, ar1 = {0.f, 0.f};
      float2_t az0 = {0.f, 0.f}, az1 = {0.f, 0.f};
      float2_t an0 = {0.f, 0.f}, an1 = {0.f, 0.f};
      const float4_t* hb4 = (const float4_t*)hbuf;
#pragma unroll
      for (int c = 0; c < 16; c++) {
        const float4_t hv = hb4[c];             // ds_read_b128, uniform addr = broadcast
        const float2_t h0 = {hv.x, hv.y};
        const float2_t h1 = {hv.z, hv.w};
        const int k = c * 2;
        ar0 = __builtin_elementwise_fma(wr[k],     h0, ar0);   // v_pk_fma_f32
        az0 = __builtin_elementwise_fma(wz[k],     h0, az0);
        an0 = __builtin_elementwise_fma(wn[k],     h0, an0);
        ar1 = __builtin_elementwise_fma(wr[k + 1], h1, ar1);
        az1 = __builtin_elementwise_fma(wz[k + 1], h1, az1);
        an1 = __builtin_elementwise_fma(wn[k + 1], h1, an1);
      }
      const float sr = ar0.x + ar0.y + ar1.x + ar1.y;
      const float sz = az0.x + az0.y + az1.x + az1.y;
      const float sn = an0.x + an0.y + an1.x + an1.y;
      const float r = fast_sigmoid(xr + sr);
      const float z = fast_sigmoid(xz + sz);
      const float n = fast_tanh(xn + r * (sn + bh));
      h = n + z * (h - n);                      // (1-z)*n + z*h

      *hp = h;                                  // hs[t*64+j], coalesced
      hp += 64;

      // Single-wave lockstep + in-order DS ops make this safe without s_barrier.
      // asm clobbers: forbid compiler from caching hbuf across the write or
      // hoisting next iteration's LDS reads above it. No __syncthreads() here:
      // it would emit s_waitcnt vmcnt(0) and drain the gate prefetch pipeline.
      asm volatile("" ::: "memory");
      hbuf[j] = h;
      asm volatile("" ::: "memory");
    }
  }
}

// ---------------------------------------------------------------------------
// Kernel C (parallel over T): out[t][k] = hs[t] . Wend[:,perm[k]] + bend[perm[k]]
// perm = [1,0,3,2]
// ---------------------------------------------------------------------------
__global__ __launch_bounds__(256) void out_kernel(
    const float* __restrict__ hs, const float* __restrict__ Wend,
    const float* __restrict__ bend, float* __restrict__ out)
{
  __shared__ float4_t sWe[64];
  __shared__ float sbe[4];
  if (threadIdx.x < 64) sWe[threadIdx.x] = ((const float4_t*)Wend)[threadIdx.x];
  if (threadIdx.x < 4) sbe[threadIdx.x] = bend[threadIdx.x];
  __syncthreads();

  const int t = blockIdx.x * 256 + threadIdx.x;
  const float4_t* hp = (const float4_t*)(hs + (size_t)t * 64);
  float a0 = sbe[1], a1 = sbe[0], a2 = sbe[3], a3 = sbe[2];
#pragma unroll
  for (int c = 0; c < 16; c++) {
    const float4_t hv = hp[c];
#pragma unroll
    for (int q = 0; q < 4; q++) {
      const float hvq = hv[q];
      const float4_t w = sWe[c * 4 + q];   // Wend row, broadcast
      a0 += hvq * w.y;
      a1 += hvq * w.x;
      a2 += hvq * w.w;
      a3 += hvq * w.z;
    }
  }
  float4_t res = {a0, a1, a2, a3};
  ((float4_t*)out)[t] = res;
}

// ---------------------------------------------------------------------------
extern "C" void kernel_launch(void* const* d_in, const int* in_sizes, int n_in,
                              void* d_out, int out_size, void* d_ws, size_t ws_size,
                              hipStream_t stream) {
  (void)in_sizes; (void)n_in; (void)out_size; (void)ws_size;
  const float* obs  = (const float*)d_in[0];
  const float* W1   = (const float*)d_in[1];
  const float* b1   = (const float*)d_in[2];
  const float* Wir  = (const float*)d_in[3];
  const float* bir  = (const float*)d_in[4];
  const float* Wiz  = (const float*)d_in[5];
  const float* biz  = (const float*)d_in[6];
  const float* Win  = (const float*)d_in[7];
  const float* bin  = (const float*)d_in[8];
  const float* Whr  = (const float*)d_in[9];
  const float* Whz  = (const float*)d_in[10];
  const float* Whn  = (const float*)d_in[11];
  const float* bhn  = (const float*)d_in[12];
  const float* Wend = (const float*)d_in[13];
  const float* bend = (const float*)d_in[14];
  float* out = (float*)d_out;

  float* gates = (float*)d_ws;                    // [T,3,64] fp32 = 100.7 MB
  float* hs = gates + (size_t)T_LEN * 192;        // [T,64]   fp32 =  33.6 MB

  prep_kernel<<<T_LEN / 256, 256, 0, stream>>>(obs, W1, b1, Wir, bir, Wiz, biz,
                                               Win, bin, gates);
  scan_kernel<<<1, 64, 0, stream>>>(gates, Whr, Whz, Whn, bhn, hs);
  out_kernel<<<T_LEN / 256, 256, 0, stream>>>(hs, Wend, bend, out);
}

// Round 3
// 45899.991 us; speedup vs baseline: 1.0374x; 1.0374x over previous
//
#include <hip/hip_runtime.h>
#include <cstddef>

#define T_LEN 131072

typedef float float2_t __attribute__((ext_vector_type(2)));
typedef float float4_t __attribute__((ext_vector_type(4)));

__device__ __forceinline__ float fast_sigmoid(float x) {
  float e = __builtin_amdgcn_exp2f(x * -1.44269504088896340736f);
  return __builtin_amdgcn_rcpf(1.0f + e);
}

__device__ __forceinline__ float fast_tanh(float x) {
  float e = __builtin_amdgcn_exp2f(x * 2.88539008177792681472f);
  return 1.0f - 2.0f * __builtin_amdgcn_rcpf(1.0f + e);
}

// ---------------------------------------------------------------------------
// Kernel A (parallel over T): hs_in = relu(x@W1+b1); gates[t] = hs_in @ {Wir,Wiz,Win} + b
// gates layout: [T][3][64] fp32
// ---------------------------------------------------------------------------
__global__ __launch_bounds__(256) void prep_kernel(
    const float* __restrict__ obs, const float* __restrict__ W1,
    const float* __restrict__ b1,
    const float* __restrict__ Wir, const float* __restrict__ bir,
    const float* __restrict__ Wiz, const float* __restrict__ biz,
    const float* __restrict__ Win, const float* __restrict__ bin,
    float* __restrict__ gates)
{
  __shared__ float sW1[36 * 64];
  __shared__ float sWg[3 * 4096];
  __shared__ float sb1[64];
  __shared__ float sbg[3 * 64];
  for (int i = threadIdx.x; i < 36 * 64; i += 256) sW1[i] = W1[i];
  for (int i = threadIdx.x; i < 4096; i += 256) {
    sWg[i] = Wir[i];
    sWg[4096 + i] = Wiz[i];
    sWg[8192 + i] = Win[i];
  }
  if (threadIdx.x < 64) {
    sb1[threadIdx.x] = b1[threadIdx.x];
    sbg[threadIdx.x] = bir[threadIdx.x];
    sbg[64 + threadIdx.x] = biz[threadIdx.x];
    sbg[128 + threadIdx.x] = bin[threadIdx.x];
  }
  __syncthreads();

  const int t = blockIdx.x * 256 + threadIdx.x;   // T divisible by 256

  float4_t x4[9];
  {
    const float4_t* op = (const float4_t*)(obs + (size_t)t * 36);
#pragma unroll
    for (int c = 0; c < 9; c++) x4[c] = op[c];
  }
  float4_t hacc[16];
  {
    const float4_t* bv = (const float4_t*)sb1;
#pragma unroll
    for (int k = 0; k < 16; k++) hacc[k] = bv[k];
  }
#pragma unroll
  for (int c = 0; c < 9; c++) {
#pragma unroll
    for (int q = 0; q < 4; q++) {
      const float xv = x4[c][q];
      const float4_t* wrow = (const float4_t*)(sW1 + (c * 4 + q) * 64);
#pragma unroll
      for (int k = 0; k < 16; k++) hacc[k] += xv * wrow[k];
    }
  }
#pragma unroll
  for (int k = 0; k < 16; k++) {
    hacc[k].x = fmaxf(hacc[k].x, 0.0f);
    hacc[k].y = fmaxf(hacc[k].y, 0.0f);
    hacc[k].z = fmaxf(hacc[k].z, 0.0f);
    hacc[k].w = fmaxf(hacc[k].w, 0.0f);
  }

  float* gout = gates + (size_t)t * 192;
  for (int g = 0; g < 3; g++) {   // rolled: caps register pressure
    const float* wg = sWg + g * 4096;
    float4_t acc[16];
    {
      const float4_t* bv = (const float4_t*)(sbg + g * 64);
#pragma unroll
      for (int k = 0; k < 16; k++) acc[k] = bv[k];
    }
#pragma unroll
    for (int ii = 0; ii < 16; ii++) {
      const float4_t hv4 = hacc[ii];
#pragma unroll
      for (int q = 0; q < 4; q++) {
        const float hv = hv4[q];
        const float4_t* wrow = (const float4_t*)(wg + (ii * 4 + q) * 64);
#pragma unroll
        for (int k = 0; k < 16; k++) acc[k] += hv * wrow[k];
      }
    }
    float4_t* outp = (float4_t*)(gout + g * 64);
#pragma unroll
    for (int k = 0; k < 16; k++) outp[k] = acc[k];
  }
}

// ---------------------------------------------------------------------------
// Kernel B (sequential): single wave, lane j owns hidden unit j. FP32.
// R2 post-mortem: VGPR_Count=132 proved the weight/ring arrays landed in
// SCRATCH (SROA runs before unrolling; loop-var-indexed allocas survive),
// costing 48KB of L1/L2 scratch reload per step (~750 cyc — matches the
// observed 870 cyc/step). Fix: NO ARRAYS — every per-lane value is an
// individually named variable via X-macros, literal indices only.
// ---------------------------------------------------------------------------
#define REP16(X) X(0) X(1) X(2) X(3) X(4) X(5) X(6) X(7) \
                 X(8) X(9) X(10) X(11) X(12) X(13) X(14) X(15)
#define REP4(X) X(0) X(1) X(2) X(3)

// weight registers: chunk i covers h-elements 4i..4i+3; A = first pair, B = second
#define DECLW(i) float2_t wrA##i, wrB##i, wzA##i, wzB##i, wnA##i, wnB##i;

#define INITW(i) \
  wrA##i = float2_t{sW[(4*i)*64+j],        sW[(4*i+1)*64+j]}; \
  wrB##i = float2_t{sW[(4*i+2)*64+j],      sW[(4*i+3)*64+j]}; \
  wzA##i = float2_t{sW[4096+(4*i)*64+j],   sW[4096+(4*i+1)*64+j]}; \
  wzB##i = float2_t{sW[4096+(4*i+2)*64+j], sW[4096+(4*i+3)*64+j]}; \
  wnA##i = float2_t{sW[8192+(4*i)*64+j],   sW[8192+(4*i+1)*64+j]}; \
  wnB##i = float2_t{sW[8192+(4*i+2)*64+j], sW[8192+(4*i+3)*64+j]};

// one float4 chunk of the three matvecs: 6 v_pk_fma_f32
#define GSTEP(i) { \
  const float4_t hv = hb4[i];  /* ds_read_b128, uniform addr = broadcast */ \
  const float2_t hA = {hv.x, hv.y}, hB = {hv.z, hv.w}; \
  ar0 = __builtin_elementwise_fma(wrA##i, hA, ar0); \
  az0 = __builtin_elementwise_fma(wzA##i, hA, az0); \
  an0 = __builtin_elementwise_fma(wnA##i, hA, an0); \
  ar1 = __builtin_elementwise_fma(wrB##i, hB, ar1); \
  az1 = __builtin_elementwise_fma(wzB##i, hB, az1); \
  an1 = __builtin_elementwise_fma(wnB##i, hB, an1); }

#define DECLP(d) float pr##d, pz##d, pn##d;
#define PROLOAD(d) \
  pr##d = g0[(size_t)(d) * 192]; \
  pz##d = g0[(size_t)(d) * 192 + 64]; \
  pn##d = g0[(size_t)(d) * 192 + 128];

// one full GRU step, prefetch slot d (numerics identical to R2)
#define STEP(d) { \
  const float xr = pr##d, xz = pz##d, xn = pn##d; \
  pr##d = gpf[0]; pz##d = gpf[64]; pn##d = gpf[128]; gpf += 192; \
  float2_t ar0 = {0.f,0.f}, ar1 = {0.f,0.f}; \
  float2_t az0 = {0.f,0.f}, az1 = {0.f,0.f}; \
  float2_t an0 = {0.f,0.f}, an1 = {0.f,0.f}; \
  REP16(GSTEP) \
  const float2_t ars = ar0 + ar1, azs = az0 + az1, ans = an0 + an1; \
  const float r = fast_sigmoid(xr + (ars.x + ars.y)); \
  const float z = fast_sigmoid(xz + (azs.x + azs.y)); \
  const float n = fast_tanh(xn + r * ((ans.x + ans.y) + bh)); \
  h = n + z * (h - n);                       /* (1-z)*n + z*h */ \
  *hp = h; hp += 64;                         /* hs[t*64+j], coalesced */ \
  asm volatile("" ::: "memory"); \
  hbuf[j] = h; \
  asm volatile("" ::: "memory"); }

__global__ __launch_bounds__(64, 1) void scan_kernel(
    const float* __restrict__ gates,
    const float* __restrict__ Whr, const float* __restrict__ Whz,
    const float* __restrict__ Whn, const float* __restrict__ bhn,
    float* __restrict__ hs)
{
  __shared__ float sW[3 * 4096];
  __shared__ __align__(16) float hbuf[64];
  const int j = threadIdx.x;

  // stage weights coalesced, then pull column j into named float2 registers
  for (int i = j; i < 4096; i += 64) {
    sW[i] = Whr[i];
    sW[4096 + i] = Whz[i];
    sW[8192 + i] = Whn[i];
  }
  __syncthreads();

  REP16(DECLW)
  REP16(INITW)
  const float bh = bhn[j];

  float h = 0.0f;
  hbuf[j] = 0.0f;
  __syncthreads();

  // software-pipelined gate loads, distance 4 steps (gates are L2/L3-resident
  // after prep_kernel: ~300-500 cyc latency << 4 * ~380 cyc/step cover)
  REP4(DECLP)
  {
    const float* g0 = gates + j;
    REP4(PROLOAD)
  }
  const float* gpf = gates + j + (size_t)4 * 192;  // overruns 3KB past gates end: lands in hs region (values discarded, safe)
  float* hp = hs + j;
  const float4_t* hb4 = (const float4_t*)hbuf;

  for (int tb = 0; tb < T_LEN / 4; tb++) {
    STEP(0)
    STEP(1)
    STEP(2)
    STEP(3)
  }
  // Single-wave lockstep + in-order LDS pipe make the hbuf write->read safe
  // without s_barrier; asm clobbers pin the ordering against the compiler.
}

// ---------------------------------------------------------------------------
// Kernel C (parallel over T): out[t][k] = hs[t] . Wend[:,perm[k]] + bend[perm[k]]
// perm = [1,0,3,2]
// ---------------------------------------------------------------------------
__global__ __launch_bounds__(256) void out_kernel(
    const float* __restrict__ hs, const float* __restrict__ Wend,
    const float* __restrict__ bend, float* __restrict__ out)
{
  __shared__ float4_t sWe[64];
  __shared__ float sbe[4];
  if (threadIdx.x < 64) sWe[threadIdx.x] = ((const float4_t*)Wend)[threadIdx.x];
  if (threadIdx.x < 4) sbe[threadIdx.x] = bend[threadIdx.x];
  __syncthreads();

  const int t = blockIdx.x * 256 + threadIdx.x;
  const float4_t* hp = (const float4_t*)(hs + (size_t)t * 64);
  float a0 = sbe[1], a1 = sbe[0], a2 = sbe[3], a3 = sbe[2];
#pragma unroll
  for (int c = 0; c < 16; c++) {
    const float4_t hv = hp[c];
#pragma unroll
    for (int q = 0; q < 4; q++) {
      const float hvq = hv[q];
      const float4_t w = sWe[c * 4 + q];   // Wend row, broadcast
      a0 += hvq * w.y;
      a1 += hvq * w.x;
      a2 += hvq * w.w;
      a3 += hvq * w.z;
    }
  }
  float4_t res = {a0, a1, a2, a3};
  ((float4_t*)out)[t] = res;
}

// ---------------------------------------------------------------------------
extern "C" void kernel_launch(void* const* d_in, const int* in_sizes, int n_in,
                              void* d_out, int out_size, void* d_ws, size_t ws_size,
                              hipStream_t stream) {
  (void)in_sizes; (void)n_in; (void)out_size; (void)ws_size;
  const float* obs  = (const float*)d_in[0];
  const float* W1   = (const float*)d_in[1];
  const float* b1   = (const float*)d_in[2];
  const float* Wir  = (const float*)d_in[3];
  const float* bir  = (const float*)d_in[4];
  const float* Wiz  = (const float*)d_in[5];
  const float* biz  = (const float*)d_in[6];
  const float* Win  = (const float*)d_in[7];
  const float* bin  = (const float*)d_in[8];
  const float* Whr  = (const float*)d_in[9];
  const float* Whz  = (const float*)d_in[10];
  const float* Whn  = (const float*)d_in[11];
  const float* bhn  = (const float*)d_in[12];
  const float* Wend = (const float*)d_in[13];
  const float* bend = (const float*)d_in[14];
  float* out = (float*)d_out;

  float* gates = (float*)d_ws;                    // [T,3,64] fp32 = 100.7 MB
  float* hs = gates + (size_t)T_LEN * 192;        // [T,64]   fp32 =  33.6 MB

  prep_kernel<<<T_LEN / 256, 256, 0, stream>>>(obs, W1, b1, Wir, bir, Wiz, biz,
                                               Win, bin, gates);
  scan_kernel<<<1, 64, 0, stream>>>(gates, Whr, Whz, Whn, bhn, hs);
  out_kernel<<<T_LEN / 256, 256, 0, stream>>>(hs, Wend, bend, out);
}

// Round 4
// 45788.516 us; speedup vs baseline: 1.0399x; 1.0024x over previous
//
#include <hip/hip_runtime.h>
#include <cstddef>

#define T_LEN 131072

typedef float float2_t __attribute__((ext_vector_type(2)));
typedef float float4_t __attribute__((ext_vector_type(4)));

__device__ __forceinline__ float fast_sigmoid(float x) {
  float e = __builtin_amdgcn_exp2f(x * -1.44269504088896340736f);
  return __builtin_amdgcn_rcpf(1.0f + e);
}

__device__ __forceinline__ float fast_tanh(float x) {
  float e = __builtin_amdgcn_exp2f(x * 2.88539008177792681472f);
  return 1.0f - 2.0f * __builtin_amdgcn_rcpf(1.0f + e);
}

// ---------------------------------------------------------------------------
// Kernel A (parallel over T): hs_in = relu(x@W1+b1); gates[t] = hs_in @ {Wir,Wiz,Win} + b
// gates layout: [T][3][64] fp32
// ---------------------------------------------------------------------------
__global__ __launch_bounds__(256) void prep_kernel(
    const float* __restrict__ obs, const float* __restrict__ W1,
    const float* __restrict__ b1,
    const float* __restrict__ Wir, const float* __restrict__ bir,
    const float* __restrict__ Wiz, const float* __restrict__ biz,
    const float* __restrict__ Win, const float* __restrict__ bin,
    float* __restrict__ gates)
{
  __shared__ float sW1[36 * 64];
  __shared__ float sWg[3 * 4096];
  __shared__ float sb1[64];
  __shared__ float sbg[3 * 64];
  for (int i = threadIdx.x; i < 36 * 64; i += 256) sW1[i] = W1[i];
  for (int i = threadIdx.x; i < 4096; i += 256) {
    sWg[i] = Wir[i];
    sWg[4096 + i] = Wiz[i];
    sWg[8192 + i] = Win[i];
  }
  if (threadIdx.x < 64) {
    sb1[threadIdx.x] = b1[threadIdx.x];
    sbg[threadIdx.x] = bir[threadIdx.x];
    sbg[64 + threadIdx.x] = biz[threadIdx.x];
    sbg[128 + threadIdx.x] = bin[threadIdx.x];
  }
  __syncthreads();

  const int t = blockIdx.x * 256 + threadIdx.x;   // T divisible by 256

  float4_t x4[9];
  {
    const float4_t* op = (const float4_t*)(obs + (size_t)t * 36);
#pragma unroll
    for (int c = 0; c < 9; c++) x4[c] = op[c];
  }
  float4_t hacc[16];
  {
    const float4_t* bv = (const float4_t*)sb1;
#pragma unroll
    for (int k = 0; k < 16; k++) hacc[k] = bv[k];
  }
#pragma unroll
  for (int c = 0; c < 9; c++) {
#pragma unroll
    for (int q = 0; q < 4; q++) {
      const float xv = x4[c][q];
      const float4_t* wrow = (const float4_t*)(sW1 + (c * 4 + q) * 64);
#pragma unroll
      for (int k = 0; k < 16; k++) hacc[k] += xv * wrow[k];
    }
  }
#pragma unroll
  for (int k = 0; k < 16; k++) {
    hacc[k].x = fmaxf(hacc[k].x, 0.0f);
    hacc[k].y = fmaxf(hacc[k].y, 0.0f);
    hacc[k].z = fmaxf(hacc[k].z, 0.0f);
    hacc[k].w = fmaxf(hacc[k].w, 0.0f);
  }

  float* gout = gates + (size_t)t * 192;
  for (int g = 0; g < 3; g++) {   // rolled: caps register pressure
    const float* wg = sWg + g * 4096;
    float4_t acc[16];
    {
      const float4_t* bv = (const float4_t*)(sbg + g * 64);
#pragma unroll
      for (int k = 0; k < 16; k++) acc[k] = bv[k];
    }
#pragma unroll
    for (int ii = 0; ii < 16; ii++) {
      const float4_t hv4 = hacc[ii];
#pragma unroll
      for (int q = 0; q < 4; q++) {
        const float hv = hv4[q];
        const float4_t* wrow = (const float4_t*)(wg + (ii * 4 + q) * 64);
#pragma unroll
        for (int k = 0; k < 16; k++) acc[k] += hv * wrow[k];
      }
    }
    float4_t* outp = (float4_t*)(gout + g * 64);
#pragma unroll
    for (int k = 0; k < 16; k++) outp[k] = acc[k];
  }
}

// ---------------------------------------------------------------------------
// Kernel B (sequential): single wave, lane j owns hidden unit j. FP32.
// R3 post-mortem: VGPR_Count stayed 132 with named vars — the backend
// REMATERIALIZES loop-invariant ds_read weight loads inside the loop
// (ds_read is cheap-to-remat; pressure heuristic sits at the 128-reg /
// 4-wave default). 96 re-issued ds_read_b64 per step ≈ 576 cyc — matches
// the observed 840 cyc/step. Fix: launder every weight register through an
// empty inline asm ("+v") once after init. Opaque defs cannot be remat'd
// from LDS; with __launch_bounds__(64,1) the 512-VGPR budget holds them.
// ---------------------------------------------------------------------------
#define REP16(X) X(0) X(1) X(2) X(3) X(4) X(5) X(6) X(7) \
                 X(8) X(9) X(10) X(11) X(12) X(13) X(14) X(15)
#define REP4(X) X(0) X(1) X(2) X(3)

// weight registers: chunk i covers h-elements 4i..4i+3; A = first pair, B = second
#define DECLW(i) float2_t wrA##i, wrB##i, wzA##i, wzB##i, wnA##i, wnB##i;

#define INITW(i) \
  wrA##i = float2_t{sW[(4*i)*64+j],        sW[(4*i+1)*64+j]}; \
  wrB##i = float2_t{sW[(4*i+2)*64+j],      sW[(4*i+3)*64+j]}; \
  wzA##i = float2_t{sW[4096+(4*i)*64+j],   sW[4096+(4*i+1)*64+j]}; \
  wzB##i = float2_t{sW[4096+(4*i+2)*64+j], sW[4096+(4*i+3)*64+j]}; \
  wnA##i = float2_t{sW[8192+(4*i)*64+j],   sW[8192+(4*i+1)*64+j]}; \
  wnB##i = float2_t{sW[8192+(4*i+2)*64+j], sW[8192+(4*i+3)*64+j]};

// launder through asm: opaque def -> not rematerializable from LDS
#define PINW(i) asm("" : "+v"(wrA##i), "+v"(wrB##i), "+v"(wzA##i), \
                         "+v"(wzB##i), "+v"(wnA##i), "+v"(wnB##i));

// one float4 chunk of the three matvecs: 6 v_pk_fma_f32
#define GSTEP(i) { \
  const float4_t hv = hb4[i];  /* ds_read_b128, uniform addr = broadcast */ \
  const float2_t hA = {hv.x, hv.y}, hB = {hv.z, hv.w}; \
  ar0 = __builtin_elementwise_fma(wrA##i, hA, ar0); \
  az0 = __builtin_elementwise_fma(wzA##i, hA, az0); \
  an0 = __builtin_elementwise_fma(wnA##i, hA, an0); \
  ar1 = __builtin_elementwise_fma(wrB##i, hB, ar1); \
  az1 = __builtin_elementwise_fma(wzB##i, hB, az1); \
  an1 = __builtin_elementwise_fma(wnB##i, hB, an1); }

#define DECLP(d) float pr##d, pz##d, pn##d;
#define PROLOAD(d) \
  pr##d = g0[(size_t)(d) * 192]; \
  pz##d = g0[(size_t)(d) * 192 + 64]; \
  pn##d = g0[(size_t)(d) * 192 + 128];

// one full GRU step, prefetch slot d (numerics identical to R2/R3)
#define STEP(d) { \
  const float xr = pr##d, xz = pz##d, xn = pn##d; \
  pr##d = gpf[0]; pz##d = gpf[64]; pn##d = gpf[128]; gpf += 192; \
  float2_t ar0 = {0.f,0.f}, ar1 = {0.f,0.f}; \
  float2_t az0 = {0.f,0.f}, az1 = {0.f,0.f}; \
  float2_t an0 = {0.f,0.f}, an1 = {0.f,0.f}; \
  REP16(GSTEP) \
  const float2_t ars = ar0 + ar1, azs = az0 + az1, ans = an0 + an1; \
  const float r = fast_sigmoid(xr + (ars.x + ars.y)); \
  const float z = fast_sigmoid(xz + (azs.x + azs.y)); \
  const float n = fast_tanh(xn + r * ((ans.x + ans.y) + bh)); \
  h = n + z * (h - n);                       /* (1-z)*n + z*h */ \
  *hp = h; hp += 64;                         /* hs[t*64+j], coalesced */ \
  asm volatile("" ::: "memory"); \
  hbuf[j] = h; \
  asm volatile("" ::: "memory"); }

__global__ __launch_bounds__(64, 1) void scan_kernel(
    const float* __restrict__ gates,
    const float* __restrict__ Whr, const float* __restrict__ Whz,
    const float* __restrict__ Whn, const float* __restrict__ bhn,
    float* __restrict__ hs)
{
  __shared__ float sW[3 * 4096];
  __shared__ __align__(16) float hbuf[64];
  const int j = threadIdx.x;

  // stage weights coalesced, then pull column j into named float2 registers
  for (int i = j; i < 4096; i += 64) {
    sW[i] = Whr[i];
    sW[4096 + i] = Whz[i];
    sW[8192 + i] = Whn[i];
  }
  __syncthreads();

  REP16(DECLW)
  REP16(INITW)
  REP16(PINW)
  float bh = bhn[j];
  asm("" : "+v"(bh));

  float h = 0.0f;
  hbuf[j] = 0.0f;
  __syncthreads();

  // software-pipelined gate loads, distance 4 steps (gates are L2/L3-resident
  // after prep_kernel: ~300-500 cyc latency << 4 * ~400 cyc/step cover)
  REP4(DECLP)
  {
    const float* g0 = gates + j;
    REP4(PROLOAD)
  }
  const float* gpf = gates + j + (size_t)4 * 192;  // overruns 3KB past gates end: lands in hs region (values discarded, safe)
  float* hp = hs + j;
  const float4_t* hb4 = (const float4_t*)hbuf;

  for (int tb = 0; tb < T_LEN / 4; tb++) {
    STEP(0)
    STEP(1)
    STEP(2)
    STEP(3)
  }
  // Single-wave lockstep + in-order LDS pipe make the hbuf write->read safe
  // without s_barrier; asm clobbers pin the ordering against the compiler.
}

// ---------------------------------------------------------------------------
// Kernel C (parallel over T): out[t][k] = hs[t] . Wend[:,perm[k]] + bend[perm[k]]
// perm = [1,0,3,2]
// ---------------------------------------------------------------------------
__global__ __launch_bounds__(256) void out_kernel(
    const float* __restrict__ hs, const float* __restrict__ Wend,
    const float* __restrict__ bend, float* __restrict__ out)
{
  __shared__ float4_t sWe[64];
  __shared__ float sbe[4];
  if (threadIdx.x < 64) sWe[threadIdx.x] = ((const float4_t*)Wend)[threadIdx.x];
  if (threadIdx.x < 4) sbe[threadIdx.x] = bend[threadIdx.x];
  __syncthreads();

  const int t = blockIdx.x * 256 + threadIdx.x;
  const float4_t* hp = (const float4_t*)(hs + (size_t)t * 64);
  float a0 = sbe[1], a1 = sbe[0], a2 = sbe[3], a3 = sbe[2];
#pragma unroll
  for (int c = 0; c < 16; c++) {
    const float4_t hv = hp[c];
#pragma unroll
    for (int q = 0; q < 4; q++) {
      const float hvq = hv[q];
      const float4_t w = sWe[c * 4 + q];   // Wend row, broadcast
      a0 += hvq * w.y;
      a1 += hvq * w.x;
      a2 += hvq * w.w;
      a3 += hvq * w.z;
    }
  }
  float4_t res = {a0, a1, a2, a3};
  ((float4_t*)out)[t] = res;
}

// ---------------------------------------------------------------------------
extern "C" void kernel_launch(void* const* d_in, const int* in_sizes, int n_in,
                              void* d_out, int out_size, void* d_ws, size_t ws_size,
                              hipStream_t stream) {
  (void)in_sizes; (void)n_in; (void)out_size; (void)ws_size;
  const float* obs  = (const float*)d_in[0];
  const float* W1   = (const float*)d_in[1];
  const float* b1   = (const float*)d_in[2];
  const float* Wir  = (const float*)d_in[3];
  const float* bir  = (const float*)d_in[4];
  const float* Wiz  = (const float*)d_in[5];
  const float* biz  = (const float*)d_in[6];
  const float* Win  = (const float*)d_in[7];
  const float* bin  = (const float*)d_in[8];
  const float* Whr  = (const float*)d_in[9];
  const float* Whz  = (const float*)d_in[10];
  const float* Whn  = (const float*)d_in[11];
  const float* bhn  = (const float*)d_in[12];
  const float* Wend = (const float*)d_in[13];
  const float* bend = (const float*)d_in[14];
  float* out = (float*)d_out;

  float* gates = (float*)d_ws;                    // [T,3,64] fp32 = 100.7 MB
  float* hs = gates + (size_t)T_LEN * 192;        // [T,64]   fp32 =  33.6 MB

  prep_kernel<<<T_LEN / 256, 256, 0, stream>>>(obs, W1, b1, Wir, bir, Wiz, biz,
                                               Win, bin, gates);
  scan_kernel<<<1, 64, 0, stream>>>(gates, Whr, Whz, Whn, bhn, hs);
  out_kernel<<<T_LEN / 256, 256, 0, stream>>>(hs, Wend, bend, out);
}